// Round 10
// baseline (90.152 us; speedup 1.0000x reference)
//
#include <hip/hip_runtime.h>
#include <hip/hip_bf16.h>

#define NROWS 16384
#define DDIM  256
#define LOG2E 1.4426950408889634f
#define SCALE 7.213475204444817f   // (1/tau) * log2(e), tau = 0.2

typedef __attribute__((ext_vector_type(4))) float f32x4;
typedef __attribute__((ext_vector_type(2))) float f32x2;
typedef __attribute__((ext_vector_type(4))) int   i32x4;
typedef __attribute__((ext_vector_type(8))) int   i32x8;

#define UNIT_SCALE 0x7F7F7F7F   // e8m0 = 127 -> 2^0 = 1.0 in all 4 bytes

// ---------------------------------------------------------------------------
// Kernel 1: L2-normalize rows of z1,z2; quantize to OCP fp8 e4m3:
//   h1q = fp8(SCALE * h1_norm)   (A side, pre-scaled so exp2(acc) is direct)
//   h2q = fp8(h2_norm)           (B side)
// exact fp32 diag logits diag5[i] = 5 * cos(z1_i, z2_i); zero rowsum.
// ---------------------------------------------------------------------------
__global__ __launch_bounds__(256) void prep_kernel(
    const float* __restrict__ z1, const float* __restrict__ z2,
    unsigned char* __restrict__ h1q, unsigned char* __restrict__ h2q,
    float* __restrict__ diag5, float* __restrict__ rowsum) {
  int tid = threadIdx.x;
  int w = tid >> 6, lane = tid & 63;
  int r = blockIdx.x * 4 + w;

  const float4 a = ((const float4*)z1)[r * 64 + lane];
  const float4 b = ((const float4*)z2)[r * 64 + lane];

  float ss1 = a.x * a.x + a.y * a.y + a.z * a.z + a.w * a.w;
  float ss2 = b.x * b.x + b.y * b.y + b.z * b.z + b.w * b.w;
  float dp  = a.x * b.x + a.y * b.y + a.z * b.z + a.w * b.w;
  #pragma unroll
  for (int m = 1; m <= 32; m <<= 1) {
    ss1 += __shfl_xor(ss1, m);
    ss2 += __shfl_xor(ss2, m);
    dp  += __shfl_xor(dp, m);
  }
  float inv1 = 1.0f / fmaxf(sqrtf(ss1), 1e-12f);
  float inv2 = 1.0f / fmaxf(sqrtf(ss2), 1e-12f);
  float s1 = inv1 * SCALE;         // fold 1/tau*log2e into A

  int p1 = __builtin_amdgcn_cvt_pk_fp8_f32(a.x * s1, a.y * s1, 0, false);
  p1     = __builtin_amdgcn_cvt_pk_fp8_f32(a.z * s1, a.w * s1, p1, true);
  int p2 = __builtin_amdgcn_cvt_pk_fp8_f32(b.x * inv2, b.y * inv2, 0, false);
  p2     = __builtin_amdgcn_cvt_pk_fp8_f32(b.z * inv2, b.w * inv2, p2, true);
  ((int*)h1q)[r * 64 + lane] = p1;
  ((int*)h2q)[r * 64 + lane] = p2;

  if (lane == 0) diag5[r] = dp * inv1 * inv2 * 5.0f;
  if (tid < 4) rowsum[blockIdx.x * 4 + tid] = 0.0f;  // 4096 blocks * 4 = 16384
}

// ---------------------------------------------------------------------------
// Kernel 2: rowsum_i = sum_j exp2(h1q_i . h2q_j) via MX-scaled fp8 MFMA
// (mfma_scale_f32_16x16x128_f8f6f4, unit e8m0 scales; MFMA floor 69K cyc/CU).
// Round-10 change: 2-deep SOFTWARE PIPELINE of the n-loop. r9 counters
// showed MfmaUtil 36% + VALUBusy 45% + idle = fully ADDITIVE pipes: exp2(n)
// was issued right after the MFMAs producing acc(n), so each wave serialized
// matrix-latency -> exp -> matrix. Now: issue MFMA(n) into accA/accB
// (named 2-state, rule-#20-safe), then run exp2 of the PREVIOUS n while the
// MFMAs execute. n=3's exp2 defers across the barrier into the next jt
// (registers survive); single tail after the loop.
// CSPL=8 -> 512 blocks = 2 blocks/CU fully resident (LDS 2x32KB, VGPR~155
// -> 3 waves/SIMD allowed, 8 waves/CU used), no tail imbalance.
// r8 PITFALL kept: global_load_lds imm offset also shifts the LDS dest ->
// always use offset 0 with explicit pointers.
// ---------------------------------------------------------------------------
#define CSPL 8
#define BN   64
#define NJT  ((NROWS / CSPL) / BN)   // 32 j-tiles per block

#define ZACC(A) do { _Pragma("unroll") \
  for (int m = 0; m < 4; ++m) A[m] = (f32x4){0.f, 0.f, 0.f, 0.f}; } while (0)

// NN is a literal -> all LDS offsets are compile-time immediates
#define DO_MFMA(NN, A) do { _Pragma("unroll") \
  for (int ks = 0; ks < 2; ++ks) { \
    i32x4 lo = *reinterpret_cast<const i32x4*>(L + pA + (NN * 4096 + ks * 128)); \
    i32x4 hi = *reinterpret_cast<const i32x4*>(L + pB + (NN * 4096 + ks * 128)); \
    union { i32x8 v; i32x4 h[2]; } u; u.h[0] = lo; u.h[1] = hi; \
    _Pragma("unroll") \
    for (int m = 0; m < 4; ++m) \
      A[m] = __builtin_amdgcn_mfma_scale_f32_16x16x128_f8f6f4( \
          afr[m][ks], u.v, A[m], 0, 0, 0, UNIT_SCALE, 0, UNIT_SCALE); \
  } } while (0)

#define DO_EXP(A) do { _Pragma("unroll") \
  for (int m = 0; m < 4; ++m) { \
    rs2[m][0] += (f32x2){__builtin_amdgcn_exp2f(A[m][0]), \
                         __builtin_amdgcn_exp2f(A[m][1])}; \
    rs2[m][1] += (f32x2){__builtin_amdgcn_exp2f(A[m][2]), \
                         __builtin_amdgcn_exp2f(A[m][3])}; \
  } } while (0)

__global__ __launch_bounds__(256) void simexp_kernel(
    const unsigned char* __restrict__ h1q, const unsigned char* __restrict__ h2q,
    float* __restrict__ rowsum) {
  __shared__ alignas(16) unsigned char lds[2][BN * DDIM];   // 2 x 16 KB

  int tid = threadIdx.x, w = tid >> 6, lane = tid & 63;
  int bx = blockIdx.x;
  int rb = bx >> 3;        // row block 0..63 (256 rows each)
  int cs = bx & 7;         // column split 0..7 == default XCD id (L2 locality)
  int row0 = rb * 256 + w * 64;
  int c0 = cs * (NROWS / CSPL);

  const char* h1b = (const char*)h1q;
  const char* h2b = (const char*)h2q;

  // A fragments: 4 row-subtiles x 2 k128-steps, 32 fp8 each -> 64 VGPRs
  i32x8 afr[4][2];
  #pragma unroll
  for (int m = 0; m < 4; ++m)
    #pragma unroll
    for (int ks = 0; ks < 2; ++ks) {
      int row = row0 + m * 16 + (lane & 15);
      int off = row * 256 + ks * 128 + (lane >> 4) * 32;   // 32B aligned
      afr[m][ks] = *reinterpret_cast<const i32x8*>(h1b + off);
    }
  #pragma unroll
  for (int m = 0; m < 4; ++m)
    #pragma unroll
    for (int ks = 0; ks < 2; ++ks)
      asm volatile("" : "+v"(afr[m][ks]));   // keep resident (no remat)

  // hoisted LDS read bases (swizzle XOR folded per-lane; n/ks stay additive)
  int sw  = (lane & 7) << 4;
  int pA  = (lane & 15) * 256 + (((lane >> 4) * 32) ^ sw);
  int pB  = (lane & 15) * 256 + ((((lane >> 4) * 32) + 16) ^ sw);

  // hoisted stage pointers (4 loads, imm offset 0 -- r8 pitfall)
  int kb = (lane & 15) * 16;
  const char* P0; const char* P1; const char* P2; const char* P3;
  {
    int r0_ = w * 16 + 0 * 4 + (lane >> 4);
    int r1_ = w * 16 + 1 * 4 + (lane >> 4);
    int r2_ = w * 16 + 2 * 4 + (lane >> 4);
    int r3_ = w * 16 + 3 * 4 + (lane >> 4);
    P0 = h2b + (size_t)(c0 + r0_) * 256 + (kb ^ ((r0_ & 7) << 4));
    P1 = h2b + (size_t)(c0 + r1_) * 256 + (kb ^ ((r1_ & 7) << 4));
    P2 = h2b + (size_t)(c0 + r2_) * 256 + (kb ^ ((r2_ & 7) << 4));
    P3 = h2b + (size_t)(c0 + r3_) * 256 + (kb ^ ((r3_ & 7) << 4));
  }

  f32x2 rs2[4][2];
  #pragma unroll
  for (int m = 0; m < 4; ++m) {
    rs2[m][0] = (f32x2){0.f, 0.f};
    rs2[m][1] = (f32x2){0.f, 0.f};
  }

  auto stage = [&](int buf) {
    __builtin_amdgcn_global_load_lds(
        (const __attribute__((address_space(1))) void*)P0,
        (__attribute__((address_space(3))) void*)&lds[buf][w * 4096 + 0 * 1024], 16, 0, 0);
    __builtin_amdgcn_global_load_lds(
        (const __attribute__((address_space(1))) void*)P1,
        (__attribute__((address_space(3))) void*)&lds[buf][w * 4096 + 1 * 1024], 16, 0, 0);
    __builtin_amdgcn_global_load_lds(
        (const __attribute__((address_space(1))) void*)P2,
        (__attribute__((address_space(3))) void*)&lds[buf][w * 4096 + 2 * 1024], 16, 0, 0);
    __builtin_amdgcn_global_load_lds(
        (const __attribute__((address_space(1))) void*)P3,
        (__attribute__((address_space(3))) void*)&lds[buf][w * 4096 + 3 * 1024], 16, 0, 0);
    P0 += 16384; P1 += 16384; P2 += 16384; P3 += 16384;
  };

  stage(0);
  __syncthreads();

  f32x4 accA[4], accB[4];

  for (int jt = 0; jt < NJT; ++jt) {
    int cur = jt & 1;
    if (jt + 1 < NJT) stage(cur ^ 1);

    const char* L = (const char*)&lds[cur][0];

    // n=0: MFMA into accA; exp2 of last jt's n=3 (accB) overlaps it
    ZACC(accA);
    DO_MFMA(0, accA);
    if (jt) DO_EXP(accB);
    // n=1: MFMA into accB; exp2(accA) overlaps
    ZACC(accB);
    DO_MFMA(1, accB);
    DO_EXP(accA);
    // n=2
    ZACC(accA);
    DO_MFMA(2, accA);
    DO_EXP(accB);
    // n=3: its exp2 defers into next jt (or the tail)
    ZACC(accB);
    DO_MFMA(3, accB);
    DO_EXP(accA);

    __syncthreads();
  }
  DO_EXP(accB);   // pipeline tail: last jt's n=3

  // reduce the 16 column-lanes (lane&15) and add to global rowsum
  #pragma unroll
  for (int m = 0; m < 4; ++m)
    #pragma unroll
    for (int p = 0; p < 2; ++p)
      #pragma unroll
      for (int c = 0; c < 2; ++c) {
        float v = rs2[m][p][c];
        v += __shfl_xor(v, 1);
        v += __shfl_xor(v, 2);
        v += __shfl_xor(v, 4);
        v += __shfl_xor(v, 8);
        if ((lane & 15) == 0)
          atomicAdd(&rowsum[row0 + m * 16 + (lane >> 4) * 4 + p * 2 + c], v);
      }
}

// ---------------------------------------------------------------------------
// Kernel 3: loss = sum_i [ log(rowsum_i - exp(diag5_i)) - diag5_i ]
// ---------------------------------------------------------------------------
__global__ __launch_bounds__(1024) void loss_kernel(
    const float* __restrict__ rowsum, const float* __restrict__ diag5,
    float* __restrict__ out) {
  int tid = threadIdx.x;
  float s = 0.0f;
  for (int i = tid; i < NROWS; i += 1024) {
    float d5 = diag5[i];
    float de = __builtin_amdgcn_exp2f(d5 * LOG2E);
    s += logf(rowsum[i] - de) - d5;
  }
  #pragma unroll
  for (int m = 1; m <= 32; m <<= 1) s += __shfl_xor(s, m);
  __shared__ float wsum[16];
  if ((tid & 63) == 0) wsum[tid >> 6] = s;
  __syncthreads();
  if (tid == 0) {
    float t = 0.0f;
    #pragma unroll
    for (int i = 0; i < 16; ++i) t += wsum[i];
    out[0] = t;
  }
}

// ---------------------------------------------------------------------------
extern "C" void kernel_launch(void* const* d_in, const int* in_sizes, int n_in,
                              void* d_out, int out_size, void* d_ws, size_t ws_size,
                              hipStream_t stream) {
  const float* z1 = (const float*)d_in[0];
  const float* z2 = (const float*)d_in[1];

  char* ws = (char*)d_ws;
  unsigned char* h1q = (unsigned char*)(ws);             // 16384*256 = 4 MB
  unsigned char* h2q = (unsigned char*)(ws + 4194304);   // 4 MB
  float* diag5 = (float*)(ws + 8388608);                 // 64 KB
  float* rowsm = (float*)(ws + 8454144);                 // 64 KB
  if (ws_size < 8519680) return;                         // fail loudly

  prep_kernel<<<4096, 256, 0, stream>>>(z1, z2, h1q, h2q, diag5, rowsm);
  simexp_kernel<<<512, 256, 0, stream>>>(h1q, h2q, rowsm);
  loss_kernel<<<1, 1024, 0, stream>>>(rowsm, diag5, (float*)d_out);
}

// Round 11
// 88.372 us; speedup vs baseline: 1.0201x; 1.0201x over previous
//
#include <hip/hip_runtime.h>
#include <hip/hip_bf16.h>

#define NROWS 16384
#define DDIM  256
#define LOG2E 1.4426950408889634f
#define SCALE 7.213475204444817f   // (1/tau) * log2(e), tau = 0.2

typedef __attribute__((ext_vector_type(4))) float f32x4;
typedef __attribute__((ext_vector_type(2))) float f32x2;
typedef __attribute__((ext_vector_type(4))) int   i32x4;
typedef __attribute__((ext_vector_type(8))) int   i32x8;

#define UNIT_SCALE 0x7F7F7F7F   // e8m0 = 127 -> 2^0 = 1.0 in all 4 bytes

// ---------------------------------------------------------------------------
// Kernel 1: L2-normalize rows of z1,z2; quantize to OCP fp8 e4m3.
//   h1q = fp8(SCALE * h1_norm)  row-major (A side, pre-scaled for exp2)
//   h2t = fp8(h2_norm) in CHUNK-TRANSPOSED layout so simexp B-fragment loads
//         are fully coalesced 1KB global_load_dwordx4:
//         T[r>>4][ks(2)][hi(2)][q(4)][r&15][16B]  (4KB per 16-row block)
//         where the 16B chunk c = byte[c*16..+16) of row r maps to
//         ks=c>>3, hi=c&1, q=(c>>1)&3.
// exact fp32 diag logits diag5[i] = 5 * cos(z1_i, z2_i); zero rowsum.
// ---------------------------------------------------------------------------
__global__ __launch_bounds__(256) void prep_kernel(
    const float* __restrict__ z1, const float* __restrict__ z2,
    unsigned char* __restrict__ h1q, unsigned char* __restrict__ h2t,
    float* __restrict__ diag5, float* __restrict__ rowsum) {
  int tid = threadIdx.x;
  int w = tid >> 6, lane = tid & 63;
  int r = blockIdx.x * 4 + w;

  const float4 a = ((const float4*)z1)[r * 64 + lane];
  const float4 b = ((const float4*)z2)[r * 64 + lane];

  float ss1 = a.x * a.x + a.y * a.y + a.z * a.z + a.w * a.w;
  float ss2 = b.x * b.x + b.y * b.y + b.z * b.z + b.w * b.w;
  float dp  = a.x * b.x + a.y * b.y + a.z * b.z + a.w * b.w;
  #pragma unroll
  for (int m = 1; m <= 32; m <<= 1) {
    ss1 += __shfl_xor(ss1, m);
    ss2 += __shfl_xor(ss2, m);
    dp  += __shfl_xor(dp, m);
  }
  float inv1 = 1.0f / fmaxf(sqrtf(ss1), 1e-12f);
  float inv2 = 1.0f / fmaxf(sqrtf(ss2), 1e-12f);
  float s1 = inv1 * SCALE;         // fold 1/tau*log2e into A

  int p1 = __builtin_amdgcn_cvt_pk_fp8_f32(a.x * s1, a.y * s1, 0, false);
  p1     = __builtin_amdgcn_cvt_pk_fp8_f32(a.z * s1, a.w * s1, p1, true);
  int p2 = __builtin_amdgcn_cvt_pk_fp8_f32(b.x * inv2, b.y * inv2, 0, false);
  p2     = __builtin_amdgcn_cvt_pk_fp8_f32(b.z * inv2, b.w * inv2, p2, true);
  ((int*)h1q)[r * 64 + lane] = p1;

  // chunk-transposed h2t write: lane holds 4B at chunk c=lane>>2, sub=lane&3
  {
    int c = lane >> 2, sub = lane & 3;
    int off = (r >> 4) * 4096 + (c >> 3) * 2048 + (c & 1) * 1024 +
              ((c >> 1) & 3) * 256 + (r & 15) * 16 + sub * 4;
    *(int*)(h2t + off) = p2;
  }

  if (lane == 0) diag5[r] = dp * inv1 * inv2 * 5.0f;
  if (tid < 4) rowsum[blockIdx.x * 4 + tid] = 0.0f;  // 4096 blocks * 4 = 16384
}

// ---------------------------------------------------------------------------
// Kernel 2: rowsum_i = sum_j exp2(h1q_i . h2_j) via MX-scaled fp8 MFMA
// (mfma_scale_f32_16x16x128_f8f6f4, unit scales; MFMA floor 70K cyc/CU).
// Round-11: LDS-FREE, BARRIER-FREE. r7-r10 were invariant at ~80us with
// MFMA 70K + VALU 85K + idle ADDITIVE: the per-jt __syncthreads phase-locked
// all waves (whole CU does exp/stage while matrix pipe idles). Now:
//  - B fragments load STRAIGHT from L2 into VGPRs: prep's chunk-transposed
//    h2t makes each fragment load a coalesced 1KB dwordx4 (base + lane*16
//    + {0,1024,2048,3072} imm), two base pointers (n=0/n=1) bumped 8192/jt.
//  - named double-buffer bufA/bufB (rule #20: literal indices only),
//    issue-early prefetch (T14): load next tile, compute current.
//  - zero-C trick: ks=0 MFMA takes a loop-invariant ZV as C -> no acc-init
//    movs at all.
//  - waves free-run (no barrier!) -> 8 waves/CU desync naturally and keep
//    the CU-level MX pipe fed; compiler inserts counted vmcnt automatically
//    (plain loads into named regs).
// Each wave: its 64 rows x ALL 2048 cols of its cs-strip, 64 tiles of 32.
// L2 dup 4x = ~2TB/s/XCD, under capacity. Grid 512 = 2 blocks/CU.
// ---------------------------------------------------------------------------
#define CSPL 8

#define LOADSET(B, P0, P1) do { \
  B[0] = *reinterpret_cast<const i32x4*>(P0); \
  B[1] = *reinterpret_cast<const i32x4*>(P0 + 1024); \
  B[2] = *reinterpret_cast<const i32x4*>(P0 + 2048); \
  B[3] = *reinterpret_cast<const i32x4*>(P0 + 3072); \
  B[4] = *reinterpret_cast<const i32x4*>(P1); \
  B[5] = *reinterpret_cast<const i32x4*>(P1 + 1024); \
  B[6] = *reinterpret_cast<const i32x4*>(P1 + 2048); \
  B[7] = *reinterpret_cast<const i32x4*>(P1 + 3072); \
  P0 += 8192; P1 += 8192; } while (0)

#define MFMA_S(Aop, Bop, Cop) \
  __builtin_amdgcn_mfma_scale_f32_16x16x128_f8f6f4( \
      Aop, Bop, Cop, 0, 0, 0, UNIT_SCALE, 0, UNIT_SCALE)

#define COMPUTE(B) do { \
  union { i32x8 v; i32x4 h[2]; } u00, u01, u10, u11; \
  u00.h[0] = B[0]; u00.h[1] = B[1]; u01.h[0] = B[2]; u01.h[1] = B[3]; \
  u10.h[0] = B[4]; u10.h[1] = B[5]; u11.h[0] = B[6]; u11.h[1] = B[7]; \
  f32x4 a0[4], a1[4]; \
  _Pragma("unroll") for (int m = 0; m < 4; ++m) a0[m] = MFMA_S(afr[m][0], u00.v, ZV); \
  _Pragma("unroll") for (int m = 0; m < 4; ++m) a1[m] = MFMA_S(afr[m][0], u10.v, ZV); \
  _Pragma("unroll") for (int m = 0; m < 4; ++m) a0[m] = MFMA_S(afr[m][1], u01.v, a0[m]); \
  _Pragma("unroll") for (int m = 0; m < 4; ++m) a1[m] = MFMA_S(afr[m][1], u11.v, a1[m]); \
  _Pragma("unroll") for (int m = 0; m < 4; ++m) { \
    rs2[m][0] += (f32x2){__builtin_amdgcn_exp2f(a0[m][0]), __builtin_amdgcn_exp2f(a0[m][1])}; \
    rs2[m][1] += (f32x2){__builtin_amdgcn_exp2f(a0[m][2]), __builtin_amdgcn_exp2f(a0[m][3])}; \
    rs2[m][0] += (f32x2){__builtin_amdgcn_exp2f(a1[m][0]), __builtin_amdgcn_exp2f(a1[m][1])}; \
    rs2[m][1] += (f32x2){__builtin_amdgcn_exp2f(a1[m][2]), __builtin_amdgcn_exp2f(a1[m][3])}; \
  } } while (0)

__global__ __launch_bounds__(256) void simexp_kernel(
    const unsigned char* __restrict__ h1q, const unsigned char* __restrict__ h2t,
    float* __restrict__ rowsum) {
  int tid = threadIdx.x, w = tid >> 6, lane = tid & 63;
  int bx = blockIdx.x;
  int rb = bx >> 3;        // row block 0..63 (256 rows each)
  int cs = bx & 7;         // column split 0..7 == default XCD id (L2 locality)
  int row0 = rb * 256 + w * 64;

  const char* h1b = (const char*)h1q;

  // A fragments: 4 row-subtiles x 2 k128-steps, 32 fp8 each -> 64 VGPRs
  i32x8 afr[4][2];
  #pragma unroll
  for (int m = 0; m < 4; ++m)
    #pragma unroll
    for (int ks = 0; ks < 2; ++ks) {
      int row = row0 + m * 16 + (lane & 15);
      int off = row * 256 + ks * 128 + (lane >> 4) * 32;   // 32B aligned
      afr[m][ks] = *reinterpret_cast<const i32x8*>(h1b + off);
    }
  #pragma unroll
  for (int m = 0; m < 4; ++m)
    #pragma unroll
    for (int ks = 0; ks < 2; ++ks)
      asm volatile("" : "+v"(afr[m][ks]));   // keep resident (no remat)

  // B-fragment base pointers into the chunk-transposed strip:
  // strip base = cs * 2048 rows * 256B; per 32-col tile: n=0 block at +0,
  // n=1 block at +4096; per-lane addr = base + lane*16; bump 8192/tile.
  const char* Bp0 = (const char*)h2t + (size_t)cs * 524288 + lane * 16;
  const char* Bp1 = Bp0 + 4096;

  const f32x4 ZV = {0.f, 0.f, 0.f, 0.f};
  f32x2 rs2[4][2];
  #pragma unroll
  for (int m = 0; m < 4; ++m) {
    rs2[m][0] = (f32x2){0.f, 0.f};
    rs2[m][1] = (f32x2){0.f, 0.f};
  }

  i32x4 bufA[8], bufB[8];
  LOADSET(bufA, Bp0, Bp1);          // prime tile 0

  for (int jt2 = 0; jt2 < 32; ++jt2) {
    LOADSET(bufB, Bp0, Bp1);        // prefetch tile 2*jt2+1
    COMPUTE(bufA);                  // compute tile 2*jt2
    LOADSET(bufA, Bp0, Bp1);        // prefetch tile 2*jt2+2 (last iter: OOB
                                    // into 32KB ws slack, never computed)
    COMPUTE(bufB);                  // compute tile 2*jt2+1
  }

  // reduce the 16 column-lanes (lane&15) and add to global rowsum
  #pragma unroll
  for (int m = 0; m < 4; ++m)
    #pragma unroll
    for (int p = 0; p < 2; ++p)
      #pragma unroll
      for (int c = 0; c < 2; ++c) {
        float v = rs2[m][p][c];
        v += __shfl_xor(v, 1);
        v += __shfl_xor(v, 2);
        v += __shfl_xor(v, 4);
        v += __shfl_xor(v, 8);
        if ((lane & 15) == 0)
          atomicAdd(&rowsum[row0 + m * 16 + (lane >> 4) * 4 + p * 2 + c], v);
      }
}

// ---------------------------------------------------------------------------
// Kernel 3: loss = sum_i [ log(rowsum_i - exp(diag5_i)) - diag5_i ]
// ---------------------------------------------------------------------------
__global__ __launch_bounds__(1024) void loss_kernel(
    const float* __restrict__ rowsum, const float* __restrict__ diag5,
    float* __restrict__ out) {
  int tid = threadIdx.x;
  float s = 0.0f;
  for (int i = tid; i < NROWS; i += 1024) {
    float d5 = diag5[i];
    float de = __builtin_amdgcn_exp2f(d5 * LOG2E);
    s += logf(rowsum[i] - de) - d5;
  }
  #pragma unroll
  for (int m = 1; m <= 32; m <<= 1) s += __shfl_xor(s, m);
  __shared__ float wsum[16];
  if ((tid & 63) == 0) wsum[tid >> 6] = s;
  __syncthreads();
  if (tid == 0) {
    float t = 0.0f;
    #pragma unroll
    for (int i = 0; i < 16; ++i) t += wsum[i];
    out[0] = t;
  }
}

// ---------------------------------------------------------------------------
extern "C" void kernel_launch(void* const* d_in, const int* in_sizes, int n_in,
                              void* d_out, int out_size, void* d_ws, size_t ws_size,
                              hipStream_t stream) {
  const float* z1 = (const float*)d_in[0];
  const float* z2 = (const float*)d_in[1];

  char* ws = (char*)d_ws;
  unsigned char* h1q = (unsigned char*)(ws);             // 4 MB
  unsigned char* h2t = (unsigned char*)(ws + 4194304);   // 4 MB + 32KB slack
  float* diag5 = (float*)(ws + 8421376);                 // 64 KB
  float* rowsm = (float*)(ws + 8486912);                 // 64 KB
  if (ws_size < 8552448) return;                         // fail loudly

  prep_kernel<<<4096, 256, 0, stream>>>(z1, z2, h1q, h2t, diag5, rowsm);
  simexp_kernel<<<512, 256, 0, stream>>>(h1q, h2t, rowsm);
  loss_kernel<<<1, 1024, 0, stream>>>(rowsm, diag5, (float*)d_out);
}